// Round 9
// baseline (2757.068 us; speedup 1.0000x reference)
//
#include <hip/hip_runtime.h>
#include <hip/hip_bf16.h>
#include <cstddef>
#include <cstdint>

#define PP 32
#define BB 64
#define TT 100
#define WW 50
#define EE 64
#define HH 256
// ALPHA = 0.5, (1-ALPHA)/P = 0.015625

typedef float f4 __attribute__((ext_vector_type(4)));
typedef __attribute__((ext_vector_type(8))) short short8;   // 8 bf16 (4 VGPRs)
typedef __attribute__((ext_vector_type(4))) float f32x4;

__device__ __forceinline__ float sigm(float x) { return 1.0f / (1.0f + expf(-x)); }
__device__ __forceinline__ float splus(float x) {
    return fmaxf(x, 0.0f) + log1pf(expf(-fabsf(x)));
}
__device__ __forceinline__ unsigned short bfh(float x) {
    __hip_bfloat16 h = __float2bfloat16(x);           // RNE
    return *reinterpret_cast<unsigned short*>(&h);
}
__device__ __forceinline__ float bff(unsigned short u) {
    __hip_bfloat16 h; *reinterpret_cast<unsigned short*>(&h) = u;
    return __bfloat162float(h);
}

// ---------------------------------------------------------------------------
// Prologue A: emb = relu(prev_window @ W_act + b_act) -> bf16 hi/lo split
// [t][b][e]; xobs[t*64+b] = emb . W_obs[256:320] + b_obs (fp32 exact path)
// ---------------------------------------------------------------------------
__global__ __launch_bounds__(256) void k_emb(
    const float* __restrict__ pw, const float* __restrict__ w_act,
    const float* __restrict__ b_act, const float* __restrict__ w_obs,
    const float* __restrict__ b_obs,
    unsigned short* __restrict__ embh, unsigned short* __restrict__ embl,
    float* __restrict__ xobs)
{
    int tid = threadIdx.x;
    int sub = tid >> 6;
    int e   = tid & 63;
    int bt  = blockIdx.x * 4 + sub;   // = b*100 + t
    int b = bt / TT, t = bt % TT;

    __shared__ float pws[4][WW + 2];
    if (e < WW) pws[sub][e] = pw[(size_t)bt * WW + e];
    __syncthreads();

    float acc = b_act[e];
    #pragma unroll 5
    for (int w = 0; w < WW; ++w) acc += pws[sub][w] * w_act[w * EE + e];
    float r = fmaxf(acc, 0.0f);

    unsigned short uh = bfh(r);
    embh[((size_t)t * BB + b) * EE + e] = uh;
    embl[((size_t)t * BB + b) * EE + e] = bfh(r - bff(uh));

    float xv = r * w_obs[HH + e];
    #pragma unroll
    for (int d = 1; d < 64; d <<= 1) xv += __shfl_xor(xv, d);
    if (e == 0) xobs[t * BB + b] = xv + b_obs[0];
}

// ---------------------------------------------------------------------------
// Prologue B: pack weights into MFMA-fragment order, bf16 hi/lo.
// Layout: [colp 16][bidx 20][g 5][lane 64][e 8] (ushort).
//   bidx 0..9  = hi chunks (k = bidx*32 + (lane>>4)*8 + e)
//   bidx 10..19 = lo chunks
//   col = g*256 + colp*16 + (lane&15); k<256 from W_hh, else W_ih.
// ---------------------------------------------------------------------------
__global__ __launch_bounds__(256) void k_packB(
    const float* __restrict__ W_ih, const float* __restrict__ W_hh,
    unsigned short* __restrict__ Bp)
{
    int i = blockIdx.x * 256 + threadIdx.x;    // 819200 total
    int colp = i / 51200;  int r = i - colp * 51200;
    int bidx = r / 2560;   r -= bidx * 2560;
    int g    = r / 512;    r -= g * 512;
    int lane = r >> 3;     int e = r & 7;

    int c = (bidx < 10) ? bidx : (bidx - 10);
    int k = c * 32 + (lane >> 4) * 8 + e;
    int col = g * HH + colp * 16 + (lane & 15);
    float w = (k < HH) ? W_hh[(size_t)k * 1280 + col]
                       : W_ih[(size_t)(k - HH) * 1280 + col];
    unsigned short uh = bfh(w);
    Bp[i] = (bidx < 10) ? uh : bfh(w - bff(uh));
}

// ---------------------------------------------------------------------------
// Prologue C: split h0 into bf16 hi/lo (into parity-A h buffers); copy c0.
// ---------------------------------------------------------------------------
__global__ __launch_bounds__(256) void k_split0(
    const float* __restrict__ h0, const float* __restrict__ c0,
    unsigned short* __restrict__ hh, unsigned short* __restrict__ hl,
    float* __restrict__ cc)
{
    int i = blockIdx.x * 256 + threadIdx.x;    // 524288
    float v = h0[i];
    unsigned short uh = bfh(v);
    hh[i] = uh;
    hl[i] = bfh(v - bff(uh));
    cc[i] = c0[i];
}

// ---------------------------------------------------------------------------
// S1: MFMA GEMM + LSTM elementwise + partial output dots.  Per step.
// grid 256 blocks = (rgrp 0..15, cp 0..15) x 256 thr (4 waves, 1 blk/CU).
// Wave w: rows rg*32..+32 (TWO 16-row A frags, rg = rgrp*4+w) x 16 hcols
// (cp) x 5 gates.  Both frags share every B frag -> B traffic halves.
// Single-pass K: per slice cs (0..9) load Ah[2],Al[2] + Bh[5],Bl[5],
// issue 30 MFMAs (Ah*Bh, Ah*Bl, Al*Bh per gate x 2 frags).  K_eff = 960.
// A/B direct from global (B frag-ordered, L1/L2-hot).  No LDS, no syncs.
// ---------------------------------------------------------------------------
__global__ __launch_bounds__(256, 1) void s1_mfma(
    const unsigned short* __restrict__ Bp,
    const unsigned short* __restrict__ embh_t, const unsigned short* __restrict__ embl_t,
    const unsigned short* __restrict__ hh_in, const unsigned short* __restrict__ hl_in,
    const float* __restrict__ c_in,
    unsigned short* __restrict__ hh_out, unsigned short* __restrict__ hl_out,
    float* __restrict__ c_out,
    const int* __restrict__ gidx,            // null at t=0 (identity)
    const float* __restrict__ b_ih, const float* __restrict__ b_hh,
    const float* __restrict__ w_obs, const float* __restrict__ w_lab,
    const float* __restrict__ eps_t,
    float* __restrict__ dpo, float* __restrict__ dpl)   // [16][2048] each
{
    const int tid  = threadIdx.x;
    const int rgrp = blockIdx.x >> 4;   // 0..15
    const int cp   = blockIdx.x & 15;   // 0..15
    const int lane = tid & 63;
    const int w    = tid >> 6;          // wave 0..3
    const int lh   = lane & 15;
    const int kq   = lane >> 4;         // 0..3
    const int rg   = rgrp * 4 + w;      // 0..63 (32 rows each)
    const int R0   = rg * 32;

    // ---- A-frag base addresses (gather-on-read via gidx), 2 frags
    size_t hoff[2], eoff[2];
    #pragma unroll
    for (int fr = 0; fr < 2; ++fr) {
        int myrow = R0 + fr * 16 + lh;
        int sr    = gidx ? gidx[myrow] : myrow;
        hoff[fr] = (size_t)sr * 512 + (size_t)kq * 16;            // bytes
        eoff[fr] = (size_t)(myrow & 63) * 128 + (size_t)kq * 16;  // bytes
    }

    f32x4 acc0[5], acc1[5];
    #pragma unroll
    for (int g = 0; g < 5; ++g) { acc0[g] = (f32x4)(0.0f); acc1[g] = (f32x4)(0.0f); }

    const char* hhp = (const char*)hh_in;
    const char* hlp = (const char*)hl_in;
    const char* ehp = (const char*)embh_t;
    const char* elp = (const char*)embl_t;
    const short8* bslab = (const short8*)Bp + (size_t)cp * 6400 + lane;
    // Bh frag (cs,g): bslab[(cs*5+g)*64] ; Bl frag: bslab[((cs+10)*5+g)*64]

    #pragma unroll
    for (int cs = 0; cs < 10; ++cs) {
        short8 Ah0, Al0, Ah1, Al1;
        if (cs < 8) {
            Ah0 = *(const short8*)(hhp + hoff[0] + cs * 64);
            Al0 = *(const short8*)(hlp + hoff[0] + cs * 64);
            Ah1 = *(const short8*)(hhp + hoff[1] + cs * 64);
            Al1 = *(const short8*)(hlp + hoff[1] + cs * 64);
        } else {
            Ah0 = *(const short8*)(ehp + eoff[0] + (cs - 8) * 64);
            Al0 = *(const short8*)(elp + eoff[0] + (cs - 8) * 64);
            Ah1 = *(const short8*)(ehp + eoff[1] + (cs - 8) * 64);
            Al1 = *(const short8*)(elp + eoff[1] + (cs - 8) * 64);
        }
        short8 Bh[5], Bl[5];
        #pragma unroll
        for (int g = 0; g < 5; ++g) {
            Bh[g] = bslab[(cs * 5 + g) * 64];
            Bl[g] = bslab[((cs + 10) * 5 + g) * 64];
        }
        // per-acc order matches round 8: Ah*Bh, Ah*Bl, Al*Bh
        #pragma unroll
        for (int g = 0; g < 5; ++g) {
            acc0[g] = __builtin_amdgcn_mfma_f32_16x16x32_bf16(Ah0, Bh[g], acc0[g], 0, 0, 0);
            acc1[g] = __builtin_amdgcn_mfma_f32_16x16x32_bf16(Ah1, Bh[g], acc1[g], 0, 0, 0);
        }
        #pragma unroll
        for (int g = 0; g < 5; ++g) {
            acc0[g] = __builtin_amdgcn_mfma_f32_16x16x32_bf16(Ah0, Bl[g], acc0[g], 0, 0, 0);
            acc1[g] = __builtin_amdgcn_mfma_f32_16x16x32_bf16(Ah1, Bl[g], acc1[g], 0, 0, 0);
        }
        #pragma unroll
        for (int g = 0; g < 5; ++g) {
            acc0[g] = __builtin_amdgcn_mfma_f32_16x16x32_bf16(Al0, Bh[g], acc0[g], 0, 0, 0);
            acc1[g] = __builtin_amdgcn_mfma_f32_16x16x32_bf16(Al1, Bh[g], acc1[g], 0, 0, 0);
        }
    }

    // ---- epilogue (C-layout: col = lane&15, row = (lane>>4)*4 + reg)
    const int hcol = cp * 16 + lh;
    float bsum[5];
    #pragma unroll
    for (int g = 0; g < 5; ++g) bsum[g] = b_ih[g * HH + hcol] + b_hh[g * HH + hcol];
    const float wobs_l = w_obs[hcol];
    const float wlab_l = w_lab[hcol];

    #pragma unroll
    for (int fr = 0; fr < 2; ++fr) {
        #pragma unroll
        for (int reg = 0; reg < 4; ++reg) {
            int row = R0 + fr * 16 + kq * 4 + reg;
            int sr2 = gidx ? gidx[row] : row;
            float cpv = c_in[(size_t)sr2 * HH + hcol];
            float ep  = eps_t[(size_t)row * HH + hcol];

            const f32x4* ac = fr ? acc1 : acc0;
            float gi = ac[0][reg] + bsum[0];
            float gf = ac[1][reg] + bsum[1];
            float gg = ac[2][reg] + bsum[2];
            float go = ac[3][reg] + bsum[3];
            float gv = ac[4][reg] + bsum[4];

            float mu  = sigm(gf) * cpv + sigm(gi) * tanhf(gg);
            float c1v = mu + splus(gv) * ep;
            float h1v = sigm(go) * tanhf(c1v);

            c_out[(size_t)row * HH + hcol] = c1v;
            unsigned short uh = bfh(h1v);
            hh_out[(size_t)row * HH + hcol] = uh;
            hl_out[(size_t)row * HH + hcol] = bfh(h1v - bff(uh));

            float po = h1v * wobs_l, pl = h1v * wlab_l;
            po += __shfl_xor(po, 1); po += __shfl_xor(po, 2);
            po += __shfl_xor(po, 4); po += __shfl_xor(po, 8);
            pl += __shfl_xor(pl, 1); pl += __shfl_xor(pl, 2);
            pl += __shfl_xor(pl, 4); pl += __shfl_xor(pl, 8);
            if (lh == 0) {
                dpo[cp * 2048 + row] = po;
                dpl[cp * 2048 + row] = pl;
            }
        }
    }
}

// ---------------------------------------------------------------------------
// S2: per batch-column b (64 blocks x 256 thr): reduce 16 partial dots,
// log-softmax over P, gumbel-argmax, write gidx, emit pf_out and y_out.
// ---------------------------------------------------------------------------
__global__ __launch_bounds__(256) void s2_kernel(
    const float* __restrict__ dpo, const float* __restrict__ dpl,
    const float* __restrict__ xobs_t, const float* __restrict__ g_t,
    const float* __restrict__ b_lab,
    float* __restrict__ p_buf, int first,
    int* __restrict__ gidx_next,
    float* __restrict__ y_out_t, float* __restrict__ pf_out_t)
{
    int b   = blockIdx.x;
    int tid = threadIdx.x;

    __shared__ float gt[PP][PP + 1];
    __shared__ float lg[PP];
    __shared__ float w1s[PP];
    __shared__ float lgt[PP];
    __shared__ float pnew[PP];
    __shared__ float dpart[PP];
    __shared__ int   idxs[PP];

    // stage gumbel tile (32x32), 256 threads x 1 float4
    {
        f4 v = ((const f4*)(g_t + (size_t)b * 1024))[tid];
        int p = tid >> 3, j0 = (tid & 7) * 4;
        gt[p][j0 + 0] = v.x; gt[p][j0 + 1] = v.y;
        gt[p][j0 + 2] = v.z; gt[p][j0 + 3] = v.w;
    }

    int p = tid >> 3, j = tid & 7;
    // reduce 16 dpo partials: thread (p, j) takes ct = j and j+8
    {
        int o = p * BB + b;
        float s = dpo[j * 2048 + o] + dpo[(j + 8) * 2048 + o];
        s += __shfl_xor(s, 1); s += __shfl_xor(s, 2); s += __shfl_xor(s, 4);
        if (j == 0) {
            float pprev = first ? -3.4657359027997265f : p_buf[o];
            lg[p] = pprev + s + xobs_t[b];
        }
    }
    __syncthreads();

    // log-softmax over P; w1; logits
    if (tid < 32) {
        float v = lg[tid];
        float m = v;
        #pragma unroll
        for (int d = 1; d < 32; d <<= 1) m = fmaxf(m, __shfl_xor(m, d));
        float e = expf(v - m), se = e;
        #pragma unroll
        for (int d = 1; d < 32; d <<= 1) se += __shfl_xor(se, d);
        float l1 = v - m - logf(se);
        float w1 = expf(l1);
        w1s[tid] = w1;
        lgt[tid] = logf(0.5f * w1 + 0.015625f);
    }
    __syncthreads();

    // gumbel-argmax resample; new weights; p_new
    if (tid < 32) {
        int p2 = tid;
        float best = -INFINITY; int bi = 0;
        #pragma unroll 8
        for (int jj = 0; jj < 32; ++jj) {
            float val = lgt[jj] + gt[p2][jj];
            if (val > best) { best = val; bi = jj; }   // first max, like jnp.argmax
        }
        idxs[p2] = bi;
        gidx_next[p2 * BB + b] = bi * BB + b;

        float wv = w1s[bi];
        wv = wv / (0.5f * wv + 0.015625f);
        float lw = logf(wv);
        float m2 = lw;
        #pragma unroll
        for (int d = 1; d < 32; d <<= 1) m2 = fmaxf(m2, __shfl_xor(m2, d));
        float e2 = expf(lw - m2), s2 = e2;
        #pragma unroll
        for (int d = 1; d < 32; d <<= 1) s2 += __shfl_xor(s2, d);
        float pn = lw - m2 - logf(s2);
        pnew[p2] = pn;
        p_buf[p2 * BB + b] = pn;
    }
    __syncthreads();

    // reduce 16 dpl partials at resampled rows
    {
        int src = idxs[p] * BB + b;
        float d = dpl[j * 2048 + src] + dpl[(j + 8) * 2048 + src];
        d += __shfl_xor(d, 1); d += __shfl_xor(d, 2); d += __shfl_xor(d, 4);
        if (j == 0) dpart[p] = d;
    }
    __syncthreads();

    if (tid < 32) {
        float dd = dpart[tid];
        float bl = b_lab[0];
        pf_out_t[tid * BB + b] = 1.0f / (1.0f + expf(-(dd + bl)));
        float contrib = expf(pnew[tid]) * dd;
        #pragma unroll
        for (int d = 1; d < 32; d <<= 1) contrib += __shfl_xor(contrib, d);
        if (tid == 0) y_out_t[b] = 1.0f / (1.0f + expf(-(contrib + bl)));
    }
}

// ---------------------------------------------------------------------------
extern "C" void kernel_launch(void* const* d_in, const int* in_sizes, int n_in,
                              void* d_out, int out_size, void* d_ws, size_t ws_size,
                              hipStream_t stream)
{
    const float* prev_window = (const float*)d_in[0];
    const float* h0    = (const float*)d_in[1];
    const float* c0    = (const float*)d_in[2];
    const float* eps   = (const float*)d_in[3];
    const float* gum   = (const float*)d_in[4];
    const float* W_act = (const float*)d_in[5];
    const float* b_act = (const float*)d_in[6];
    const float* W_ih  = (const float*)d_in[7];
    const float* b_ih  = (const float*)d_in[8];
    const float* W_hh  = (const float*)d_in[9];
    const float* b_hh  = (const float*)d_in[10];
    const float* W_obs = (const float*)d_in[11];
    const float* b_obs = (const float*)d_in[12];
    const float* W_lab = (const float*)d_in[13];
    const float* b_lab = (const float*)d_in[14];

    float* out = (float*)d_out;           // [T*B] y_out, then [T*P*B] pf_out
    char* w = (char*)d_ws;

    unsigned short* Bp   = (unsigned short*)(w);               // 1,638,400 B
    unsigned short* embh = (unsigned short*)(w + 1638400);     //   819,200
    unsigned short* embl = (unsigned short*)(w + 2457600);     //   819,200
    unsigned short* hhA  = (unsigned short*)(w + 3276800);     // 1,048,576
    unsigned short* hlA  = (unsigned short*)(w + 4325376);
    unsigned short* hhB  = (unsigned short*)(w + 5373952);
    unsigned short* hlB  = (unsigned short*)(w + 6422528);
    float*  cA   = (float*)(w + 7471104);                      // 2,097,152
    float*  cB   = (float*)(w + 9568256);
    float*  xobs = (float*)(w + 11665408);                     //    25,600
    float*  pbuf = (float*)(w + 11691008);
    int*    gidx = (int*)(w + 11699200);
    float*  dpo  = (float*)(w + 11707392);                     //   131,072
    float*  dpl  = (float*)(w + 11838464);

    k_emb<<<1600, 256, 0, stream>>>(prev_window, W_act, b_act, W_obs, b_obs,
                                    embh, embl, xobs);
    k_packB<<<3200, 256, 0, stream>>>(W_ih, W_hh, Bp);
    k_split0<<<2048, 256, 0, stream>>>(h0, c0, hhA, hlA, cA);

    for (int t = 0; t < TT; ++t) {
        const unsigned short* hh_in = (t & 1) ? hhB : hhA;
        const unsigned short* hl_in = (t & 1) ? hlB : hlA;
        const float*          c_in  = (t & 1) ? cB  : cA;
        unsigned short* hh_out = (t & 1) ? hhA : hhB;
        unsigned short* hl_out = (t & 1) ? hlA : hlB;
        float*          c_out  = (t & 1) ? cA  : cB;

        s1_mfma<<<256, 256, 0, stream>>>(
            Bp, embh + (size_t)t * 4096, embl + (size_t)t * 4096,
            hh_in, hl_in, c_in, hh_out, hl_out, c_out,
            (t == 0) ? nullptr : gidx,
            b_ih, b_hh, W_obs, W_lab,
            eps + (size_t)t * 524288,
            dpo, dpl);

        s2_kernel<<<64, 256, 0, stream>>>(
            dpo, dpl, xobs + t * BB, gum + (size_t)t * 65536,
            b_lab, pbuf, (t == 0) ? 1 : 0, gidx,
            out + (size_t)t * BB,
            out + (size_t)TT * BB + (size_t)t * PP * BB);
    }
}

// Round 10
// 2405.118 us; speedup vs baseline: 1.1463x; 1.1463x over previous
//
#include <hip/hip_runtime.h>
#include <hip/hip_bf16.h>
#include <cstddef>
#include <cstdint>

#define PP 32
#define BB 64
#define TT 100
#define WW 50
#define EE 64
#define HH 256
// ALPHA = 0.5, (1-ALPHA)/P = 0.015625

typedef float f4 __attribute__((ext_vector_type(4)));
typedef __attribute__((ext_vector_type(8))) short short8;   // 8 bf16 (4 VGPRs)
typedef __attribute__((ext_vector_type(4))) float f32x4;

__device__ __forceinline__ float sigm(float x) { return 1.0f / (1.0f + expf(-x)); }
__device__ __forceinline__ float splus(float x) {
    return fmaxf(x, 0.0f) + log1pf(expf(-fabsf(x)));
}
__device__ __forceinline__ unsigned short bfh(float x) {
    __hip_bfloat16 h = __float2bfloat16(x);           // RNE
    return *reinterpret_cast<unsigned short*>(&h);
}
__device__ __forceinline__ float bff(unsigned short u) {
    __hip_bfloat16 h; *reinterpret_cast<unsigned short*>(&h) = u;
    return __bfloat162float(h);
}

// ---------------------------------------------------------------------------
// Prologue A: emb = relu(prev_window @ W_act + b_act) -> bf16 hi/lo split
// [t][b][e]; xobs[t*64+b] = emb . W_obs[256:320] + b_obs (fp32 exact path)
// ---------------------------------------------------------------------------
__global__ __launch_bounds__(256) void k_emb(
    const float* __restrict__ pw, const float* __restrict__ w_act,
    const float* __restrict__ b_act, const float* __restrict__ w_obs,
    const float* __restrict__ b_obs,
    unsigned short* __restrict__ embh, unsigned short* __restrict__ embl,
    float* __restrict__ xobs)
{
    int tid = threadIdx.x;
    int sub = tid >> 6;
    int e   = tid & 63;
    int bt  = blockIdx.x * 4 + sub;   // = b*100 + t
    int b = bt / TT, t = bt % TT;

    __shared__ float pws[4][WW + 2];
    if (e < WW) pws[sub][e] = pw[(size_t)bt * WW + e];
    __syncthreads();

    float acc = b_act[e];
    #pragma unroll 5
    for (int w = 0; w < WW; ++w) acc += pws[sub][w] * w_act[w * EE + e];
    float r = fmaxf(acc, 0.0f);

    unsigned short uh = bfh(r);
    embh[((size_t)t * BB + b) * EE + e] = uh;
    embl[((size_t)t * BB + b) * EE + e] = bfh(r - bff(uh));

    float xv = r * w_obs[HH + e];
    #pragma unroll
    for (int d = 1; d < 64; d <<= 1) xv += __shfl_xor(xv, d);
    if (e == 0) xobs[t * BB + b] = xv + b_obs[0];
}

// ---------------------------------------------------------------------------
// Prologue B: pack weights into MFMA-fragment order, bf16 hi/lo.
// Layout: [colp 16][bidx 20][g 5][lane 64][e 8] (ushort).
//   bidx 0..9  = hi chunks (k = bidx*32 + (lane>>4)*8 + e)
//   bidx 10..19 = lo chunks
//   col = g*256 + colp*16 + (lane&15); k<256 from W_hh, else W_ih.
// ---------------------------------------------------------------------------
__global__ __launch_bounds__(256) void k_packB(
    const float* __restrict__ W_ih, const float* __restrict__ W_hh,
    unsigned short* __restrict__ Bp)
{
    int i = blockIdx.x * 256 + threadIdx.x;    // 819200 total
    int colp = i / 51200;  int r = i - colp * 51200;
    int bidx = r / 2560;   r -= bidx * 2560;
    int g    = r / 512;    r -= g * 512;
    int lane = r >> 3;     int e = r & 7;

    int c = (bidx < 10) ? bidx : (bidx - 10);
    int k = c * 32 + (lane >> 4) * 8 + e;
    int col = g * HH + colp * 16 + (lane & 15);
    float w = (k < HH) ? W_hh[(size_t)k * 1280 + col]
                       : W_ih[(size_t)(k - HH) * 1280 + col];
    unsigned short uh = bfh(w);
    Bp[i] = (bidx < 10) ? uh : bfh(w - bff(uh));
}

// ---------------------------------------------------------------------------
// Prologue C: split h0 into bf16 hi/lo (into parity-A h buffers); copy c0.
// ---------------------------------------------------------------------------
__global__ __launch_bounds__(256) void k_split0(
    const float* __restrict__ h0, const float* __restrict__ c0,
    unsigned short* __restrict__ hh, unsigned short* __restrict__ hl,
    float* __restrict__ cc)
{
    int i = blockIdx.x * 256 + threadIdx.x;    // 524288
    float v = h0[i];
    unsigned short uh = bfh(v);
    hh[i] = uh;
    hl[i] = bfh(v - bff(uh));
    cc[i] = c0[i];
}

// ---------------------------------------------------------------------------
// S1: MFMA GEMM + LSTM elementwise + partial output dots.  Per step.
// grid 512 blocks = (cp = bid>>5, rp = bid&31) x 256 thr (4 waves, 2 blk/CU).
// Consecutive blocks share cp -> co-resident blocks share the B slab (L1).
// Bh (50 KB) staged in LDS (keeps 2 blocks/CU); Bl + A direct from global.
// Wave w owns rows rp*64 + w*16 .. +16 (one 16-row A frag) x 5 gate-frags.
// Single-pass K: per slice cs (0..9) load Ah,Al + Bh[5](LDS),Bl[5](global),
// issue 15 MFMAs (Ah*Bh, Ah*Bl, Al*Bh per gate).  K_eff = 960.
// ---------------------------------------------------------------------------
__global__ __launch_bounds__(256, 2) void s1_mfma(
    const unsigned short* __restrict__ Bp,
    const unsigned short* __restrict__ embh_t, const unsigned short* __restrict__ embl_t,
    const unsigned short* __restrict__ hh_in, const unsigned short* __restrict__ hl_in,
    const float* __restrict__ c_in,
    unsigned short* __restrict__ hh_out, unsigned short* __restrict__ hl_out,
    float* __restrict__ c_out,
    const int* __restrict__ gidx,            // null at t=0 (identity)
    const float* __restrict__ b_ih, const float* __restrict__ b_hh,
    const float* __restrict__ w_obs, const float* __restrict__ w_lab,
    const float* __restrict__ eps_t,
    float* __restrict__ dpo, float* __restrict__ dpl)   // [16][2048] each
{
    __shared__ short8 BhL[3200];        // [cs 10][g 5][lane 64] = 50 KB

    const int tid  = threadIdx.x;
    const int rp   = blockIdx.x & 31;   // consecutive blocks: same cp
    const int cp   = blockIdx.x >> 5;   // 0..15
    const int lane = tid & 63;
    const int w    = tid >> 6;          // wave 0..3
    const int lh   = lane & 15;
    const int kq   = lane >> 4;         // 0..3
    const int R0   = rp * 64 + w * 16;

    // ---- stage Bh chunks (bidx 0..9) into LDS, linear copy from L2-hot Bp
    {
        const short8* src = (const short8*)Bp + (size_t)cp * 6400;
        for (int s = tid; s < 3200; s += 256) BhL[s] = src[s];
    }

    // ---- A-frag base addresses (gather-on-read via gidx)
    const int myrow = R0 + lh;
    const int sr    = gidx ? gidx[myrow] : myrow;
    const size_t hoff = (size_t)sr * 512 + (size_t)kq * 16;            // bytes
    const size_t eoff = (size_t)(myrow & 63) * 128 + (size_t)kq * 16;  // bytes

    f32x4 acc[5];
    #pragma unroll
    for (int g = 0; g < 5; ++g) acc[g] = (f32x4)(0.0f);

    const char* hhp = (const char*)hh_in  + hoff;
    const char* hlp = (const char*)hl_in  + hoff;
    const char* ehp = (const char*)embh_t + eoff;
    const char* elp = (const char*)embl_t + eoff;
    const short8* bslab = (const short8*)Bp + (size_t)cp * 6400 + lane;
    // Bl frag (cs,g): bslab[((cs+10)*5+g)*64]

    __syncthreads();   // BhL ready

    #pragma unroll
    for (int cs = 0; cs < 10; ++cs) {
        short8 Ah, Al;
        if (cs < 8) {
            Ah = *(const short8*)(hhp + cs * 64);
            Al = *(const short8*)(hlp + cs * 64);
        } else {
            Ah = *(const short8*)(ehp + (cs - 8) * 64);
            Al = *(const short8*)(elp + (cs - 8) * 64);
        }
        short8 Bh[5], Bl[5];
        #pragma unroll
        for (int g = 0; g < 5; ++g) {
            Bh[g] = BhL[(cs * 5 + g) * 64 + lane];
            Bl[g] = bslab[((cs + 10) * 5 + g) * 64];
        }
        // per-acc order matches round 8: Ah*Bh, Ah*Bl, Al*Bh
        #pragma unroll
        for (int g = 0; g < 5; ++g)
            acc[g] = __builtin_amdgcn_mfma_f32_16x16x32_bf16(Ah, Bh[g], acc[g], 0, 0, 0);
        #pragma unroll
        for (int g = 0; g < 5; ++g)
            acc[g] = __builtin_amdgcn_mfma_f32_16x16x32_bf16(Ah, Bl[g], acc[g], 0, 0, 0);
        #pragma unroll
        for (int g = 0; g < 5; ++g)
            acc[g] = __builtin_amdgcn_mfma_f32_16x16x32_bf16(Al, Bh[g], acc[g], 0, 0, 0);
    }

    // ---- epilogue (C-layout: col = lane&15, row = (lane>>4)*4 + reg)
    const int hcol = cp * 16 + lh;
    float bsum[5];
    #pragma unroll
    for (int g = 0; g < 5; ++g) bsum[g] = b_ih[g * HH + hcol] + b_hh[g * HH + hcol];
    const float wobs_l = w_obs[hcol];
    const float wlab_l = w_lab[hcol];

    #pragma unroll
    for (int reg = 0; reg < 4; ++reg) {
        int row = R0 + kq * 4 + reg;
        int sr2 = gidx ? gidx[row] : row;
        float cpv = c_in[(size_t)sr2 * HH + hcol];
        float ep  = eps_t[(size_t)row * HH + hcol];

        float gi = acc[0][reg] + bsum[0];
        float gf = acc[1][reg] + bsum[1];
        float gg = acc[2][reg] + bsum[2];
        float go = acc[3][reg] + bsum[3];
        float gv = acc[4][reg] + bsum[4];

        float mu  = sigm(gf) * cpv + sigm(gi) * tanhf(gg);
        float c1v = mu + splus(gv) * ep;
        float h1v = sigm(go) * tanhf(c1v);

        c_out[(size_t)row * HH + hcol] = c1v;
        unsigned short uh = bfh(h1v);
        hh_out[(size_t)row * HH + hcol] = uh;
        hl_out[(size_t)row * HH + hcol] = bfh(h1v - bff(uh));

        float po = h1v * wobs_l, pl = h1v * wlab_l;
        po += __shfl_xor(po, 1); po += __shfl_xor(po, 2);
        po += __shfl_xor(po, 4); po += __shfl_xor(po, 8);
        pl += __shfl_xor(pl, 1); pl += __shfl_xor(pl, 2);
        pl += __shfl_xor(pl, 4); pl += __shfl_xor(pl, 8);
        if (lh == 0) {
            dpo[cp * 2048 + row] = po;
            dpl[cp * 2048 + row] = pl;
        }
    }
}

// ---------------------------------------------------------------------------
// S2: per batch-column b (64 blocks x 256 thr): reduce 16 partial dots,
// log-softmax over P, gumbel-argmax, write gidx, emit pf_out and y_out.
// ---------------------------------------------------------------------------
__global__ __launch_bounds__(256) void s2_kernel(
    const float* __restrict__ dpo, const float* __restrict__ dpl,
    const float* __restrict__ xobs_t, const float* __restrict__ g_t,
    const float* __restrict__ b_lab,
    float* __restrict__ p_buf, int first,
    int* __restrict__ gidx_next,
    float* __restrict__ y_out_t, float* __restrict__ pf_out_t)
{
    int b   = blockIdx.x;
    int tid = threadIdx.x;

    __shared__ float gt[PP][PP + 1];
    __shared__ float lg[PP];
    __shared__ float w1s[PP];
    __shared__ float lgt[PP];
    __shared__ float pnew[PP];
    __shared__ float dpart[PP];
    __shared__ int   idxs[PP];

    // stage gumbel tile (32x32), 256 threads x 1 float4
    {
        f4 v = ((const f4*)(g_t + (size_t)b * 1024))[tid];
        int p = tid >> 3, j0 = (tid & 7) * 4;
        gt[p][j0 + 0] = v.x; gt[p][j0 + 1] = v.y;
        gt[p][j0 + 2] = v.z; gt[p][j0 + 3] = v.w;
    }

    int p = tid >> 3, j = tid & 7;
    // reduce 16 dpo partials: thread (p, j) takes ct = j and j+8
    {
        int o = p * BB + b;
        float s = dpo[j * 2048 + o] + dpo[(j + 8) * 2048 + o];
        s += __shfl_xor(s, 1); s += __shfl_xor(s, 2); s += __shfl_xor(s, 4);
        if (j == 0) {
            float pprev = first ? -3.4657359027997265f : p_buf[o];
            lg[p] = pprev + s + xobs_t[b];
        }
    }
    __syncthreads();

    // log-softmax over P; w1; logits
    if (tid < 32) {
        float v = lg[tid];
        float m = v;
        #pragma unroll
        for (int d = 1; d < 32; d <<= 1) m = fmaxf(m, __shfl_xor(m, d));
        float e = expf(v - m), se = e;
        #pragma unroll
        for (int d = 1; d < 32; d <<= 1) se += __shfl_xor(se, d);
        float l1 = v - m - logf(se);
        float w1 = expf(l1);
        w1s[tid] = w1;
        lgt[tid] = logf(0.5f * w1 + 0.015625f);
    }
    __syncthreads();

    // gumbel-argmax resample; new weights; p_new
    if (tid < 32) {
        int p2 = tid;
        float best = -INFINITY; int bi = 0;
        #pragma unroll 8
        for (int jj = 0; jj < 32; ++jj) {
            float val = lgt[jj] + gt[p2][jj];
            if (val > best) { best = val; bi = jj; }   // first max, like jnp.argmax
        }
        idxs[p2] = bi;
        gidx_next[p2 * BB + b] = bi * BB + b;

        float wv = w1s[bi];
        wv = wv / (0.5f * wv + 0.015625f);
        float lw = logf(wv);
        float m2 = lw;
        #pragma unroll
        for (int d = 1; d < 32; d <<= 1) m2 = fmaxf(m2, __shfl_xor(m2, d));
        float e2 = expf(lw - m2), s2 = e2;
        #pragma unroll
        for (int d = 1; d < 32; d <<= 1) s2 += __shfl_xor(s2, d);
        float pn = lw - m2 - logf(s2);
        pnew[p2] = pn;
        p_buf[p2 * BB + b] = pn;
    }
    __syncthreads();

    // reduce 16 dpl partials at resampled rows
    {
        int src = idxs[p] * BB + b;
        float d = dpl[j * 2048 + src] + dpl[(j + 8) * 2048 + src];
        d += __shfl_xor(d, 1); d += __shfl_xor(d, 2); d += __shfl_xor(d, 4);
        if (j == 0) dpart[p] = d;
    }
    __syncthreads();

    if (tid < 32) {
        float dd = dpart[tid];
        float bl = b_lab[0];
        pf_out_t[tid * BB + b] = 1.0f / (1.0f + expf(-(dd + bl)));
        float contrib = expf(pnew[tid]) * dd;
        #pragma unroll
        for (int d = 1; d < 32; d <<= 1) contrib += __shfl_xor(contrib, d);
        if (tid == 0) y_out_t[b] = 1.0f / (1.0f + expf(-(contrib + bl)));
    }
}

// ---------------------------------------------------------------------------
extern "C" void kernel_launch(void* const* d_in, const int* in_sizes, int n_in,
                              void* d_out, int out_size, void* d_ws, size_t ws_size,
                              hipStream_t stream)
{
    const float* prev_window = (const float*)d_in[0];
    const float* h0    = (const float*)d_in[1];
    const float* c0    = (const float*)d_in[2];
    const float* eps   = (const float*)d_in[3];
    const float* gum   = (const float*)d_in[4];
    const float* W_act = (const float*)d_in[5];
    const float* b_act = (const float*)d_in[6];
    const float* W_ih  = (const float*)d_in[7];
    const float* b_ih  = (const float*)d_in[8];
    const float* W_hh  = (const float*)d_in[9];
    const float* b_hh  = (const float*)d_in[10];
    const float* W_obs = (const float*)d_in[11];
    const float* b_obs = (const float*)d_in[12];
    const float* W_lab = (const float*)d_in[13];
    const float* b_lab = (const float*)d_in[14];

    float* out = (float*)d_out;           // [T*B] y_out, then [T*P*B] pf_out
    char* w = (char*)d_ws;

    unsigned short* Bp   = (unsigned short*)(w);               // 1,638,400 B
    unsigned short* embh = (unsigned short*)(w + 1638400);     //   819,200
    unsigned short* embl = (unsigned short*)(w + 2457600);     //   819,200
    unsigned short* hhA  = (unsigned short*)(w + 3276800);     // 1,048,576
    unsigned short* hlA  = (unsigned short*)(w + 4325376);
    unsigned short* hhB  = (unsigned short*)(w + 5373952);
    unsigned short* hlB  = (unsigned short*)(w + 6422528);
    float*  cA   = (float*)(w + 7471104);                      // 2,097,152
    float*  cB   = (float*)(w + 9568256);
    float*  xobs = (float*)(w + 11665408);                     //    25,600
    float*  pbuf = (float*)(w + 11691008);
    int*    gidx = (int*)(w + 11699200);
    float*  dpo  = (float*)(w + 11707392);                     //   131,072
    float*  dpl  = (float*)(w + 11838464);

    k_emb<<<1600, 256, 0, stream>>>(prev_window, W_act, b_act, W_obs, b_obs,
                                    embh, embl, xobs);
    k_packB<<<3200, 256, 0, stream>>>(W_ih, W_hh, Bp);
    k_split0<<<2048, 256, 0, stream>>>(h0, c0, hhA, hlA, cA);

    for (int t = 0; t < TT; ++t) {
        const unsigned short* hh_in = (t & 1) ? hhB : hhA;
        const unsigned short* hl_in = (t & 1) ? hlB : hlA;
        const float*          c_in  = (t & 1) ? cB  : cA;
        unsigned short* hh_out = (t & 1) ? hhA : hhB;
        unsigned short* hl_out = (t & 1) ? hlA : hlB;
        float*          c_out  = (t & 1) ? cA  : cB;

        s1_mfma<<<512, 256, 0, stream>>>(
            Bp, embh + (size_t)t * 4096, embl + (size_t)t * 4096,
            hh_in, hl_in, c_in, hh_out, hl_out, c_out,
            (t == 0) ? nullptr : gidx,
            b_ih, b_hh, W_obs, W_lab,
            eps + (size_t)t * 524288,
            dpo, dpl);

        s2_kernel<<<64, 256, 0, stream>>>(
            dpo, dpl, xobs + t * BB, gum + (size_t)t * 65536,
            b_lab, pbuf, (t == 0) ? 1 : 0, gidx,
            out + (size_t)t * BB,
            out + (size_t)TT * BB + (size_t)t * PP * BB);
    }
}